// Round 2
// baseline (184.749 us; speedup 1.0000x reference)
//
#include <hip/hip_runtime.h>

#define EPS_F 1e-6f

// 4 threads per ray: thread g computes ray g>>2 and writes row g&3.
// Store pattern per wave: 64 lanes x 16B fully contiguous (fillBuffer-like).
__global__ __launch_bounds__(256) void mueller_kernel(
    const float* __restrict__ cos_theta_i,
    const float* __restrict__ eta_arr,
    float4* __restrict__ out, int n)
{
    int g = blockIdx.x * blockDim.x + threadIdx.x;
    int ray = g >> 2;
    int row = g & 3;
    if (ray >= n) return;

    float ci   = cos_theta_i[ray];
    float eta  = eta_arr[ray];
    float rcp_eta = 1.0f / eta;
    bool  outside = (ci >= 0.0f);
    float eta_it = outside ? eta : rcp_eta;
    float eta_ti = outside ? rcp_eta : eta;

    float cts    = 1.0f - eta_ti * eta_ti * (1.0f - ci * ci);
    float ci_abs = fabsf(ci);

    // sqrtz: complex sqrt of (cts + EPS + 0j), then mulsign by sign(cts)
    float x   = cts + EPS_F;
    float sgn = (cts >= 0.0f) ? 1.0f : -1.0f;
    float ctt_re, ctt_im;
    if (x >= 0.0f) { ctt_re = sqrtf(x) * sgn;  ctt_im = 0.0f; }
    else           { ctt_re = 0.0f;            ctt_im = sqrtf(-x) * sgn; }

    // a_s = (A - eta_it*ctt) / (A + eta_it*ctt), A = |ci|  (complex)
    float A    = ci_abs;
    float u_re = eta_it * ctt_re;
    float u_im = eta_it * ctt_im;
    float ds2  = (A + u_re) * (A + u_re) + u_im * u_im;
    float inv_ds = 1.0f / ds2;
    float as_re = (A * A - u_re * u_re - u_im * u_im) * inv_ds;
    float as_im = (-2.0f * A * u_im) * inv_ds;

    // a_p = (B - ctt) / (B + ctt), B = eta_it*|ci|  (complex)
    float B    = eta_it * ci_abs;
    float dp2  = (B + ctt_re) * (B + ctt_re) + ctt_im * ctt_im;
    float inv_dp = 1.0f / dp2;
    float ap_re = (B * B - ctt_re * ctt_re - ctt_im * ctt_im) * inv_dp;
    float ap_im = (-2.0f * B * ctt_im) * inv_dp;

    if (eta == 1.0f || eta == 0.0f) {     // dead for these inputs; fidelity
        as_re = as_im = ap_re = ap_im = 0.0f;
    }

    float r_s  = as_re * as_re + as_im * as_im;
    float r_p  = ap_re * ap_re + ap_im * ap_im;
    float prod = r_p * r_s;

    float s    = sqrtf(prod + EPS_F);     // c (>= 1e-3 here; c==0 guard dead)
    float norm = (prod == 0.0f) ? 0.0f : 1.0f / s;
    float cos_d = (ap_re * as_re + ap_im * as_im) * norm;
    float sin_d = (ap_im * as_re - ap_re * as_im) * norm;

    float a = 0.5f * (r_s + r_p);
    float b = 0.5f * (r_s - r_p);
    float cc = s * cos_d;
    float cs = s * sin_d;

    // Branch-free row select:
    // row0: (a,  b,  0,   0)    row1: (b,  a,  0,  0)
    // row2: (0,  0,  cc, -cs)   row3: (0,  0,  cs, cc)
    bool hi  = (row & 2) != 0;
    bool odd = (row & 1) != 0;
    float x0 = hi ? 0.0f : (odd ? b : a);
    float x1 = hi ? 0.0f : (odd ? a : b);
    float x2 = hi ? (odd ? cs : cc) : 0.0f;
    float x3 = hi ? (odd ? cc : -cs) : 0.0f;

    out[g] = make_float4(x0, x1, x2, x3);
}

extern "C" void kernel_launch(void* const* d_in, const int* in_sizes, int n_in,
                              void* d_out, int out_size, void* d_ws, size_t ws_size,
                              hipStream_t stream) {
    const float* ci  = (const float*)d_in[0];
    const float* eta = (const float*)d_in[1];
    float4* out = (float4*)d_out;
    int n = in_sizes[0];
    long long total = (long long)n * 4;
    int block = 256;
    long long grid = (total + block - 1) / block;
    mueller_kernel<<<(int)grid, block, 0, stream>>>(ci, eta, out, n);
}